// Round 6
// baseline (37.197 us; speedup 1.0000x reference)
//
#include <hip/hip_runtime.h>
#include <hip/hip_fp16.h>

#define NUM_F 39
#define NROW  40       // rows padded to quad multiple
#define NQ    10       // row quads
#define NTQ   55       // quad tiles (rq<=cq)
#define NSLOT 880      // NTQ*16
#define DIM   64
#define ESTRH 80       // E row stride in halves (160B): uniform 2-way banks on quad reads
#define WSTRH 72       // Wt row stride in halves (144B)

typedef float    f32x4 __attribute__((ext_vector_type(4)));
typedef _Float16 f16x8 __attribute__((ext_vector_type(8)));

union H8 {
    f16x8    v;
    __half2  h2[4];
    _Float16 h[8];
};

__global__ __launch_bounds__(256, 4) void afm_quad(
    const int*   __restrict__ feat_index,   // [B, F]
    const float* __restrict__ feat_value,   // [B, F]
    const float* __restrict__ fo_w,         // [NUM_FEATS, 1]
    const float* __restrict__ emb_table,    // [NUM_FEATS, 64]
    const float* __restrict__ att_W,        // [64, 64] (d, a)
    const float* __restrict__ att_b,        // [64]
    const float* __restrict__ att_h,        // [64]
    const float* __restrict__ p_vec,        // [64]
    const float* __restrict__ bias,         // [1]
    float*       __restrict__ out)          // [B]
{
    const int b    = blockIdx.x;
    const int t    = threadIdx.x;
    const int wave = t >> 6;
    const int lane = t & 63;
    const int la   = lane & 15;   // (ri,ci) slot within quad tile
    const int lg   = lane >> 4;   // k-group / C row-group

    __shared__ __half       e_lds[NROW][ESTRH];   // scaled embeddings, fp16
    __shared__ __half       Wt[DIM][WSTRH];       // W^T fp16: Wt[a][d]
    __shared__ float2       sq_s[NSLOT];          // {sig, q} per slot
    __shared__ float        b_lds[DIM], h_lds[DIM], pv_lds[DIM];
    __shared__ unsigned int tileQ[64];            // (validmask<<16) | (rq<<4) | cq
    __shared__ int          s_idx[NUM_F];
    __shared__ float        s_fv[NUM_F];
    __shared__ float        s_yfirst;
    __shared__ float        wred[12];             // wave partials: max, S, Q

    // ---------------- phase 0: staging ----------------
    int   my_idx = 0;
    float my_fv  = 0.f;
    if (t < NUM_F) {
        my_idx   = feat_index[b * NUM_F + t];
        my_fv    = feat_value[b * NUM_F + t];
        s_idx[t] = my_idx;
        s_fv[t]  = my_fv;
    }
    if (t < DIM) {
        b_lds[t]  = att_b[t];
        h_lds[t]  = att_h[t];
        pv_lds[t] = p_vec[t];
    }
    if (t < NQ) {   // quad-tile table with per-slot validity mask
        int rq = t;
        int off = rq * (2 * NQ + 1 - rq) / 2;   // rq*(21-rq)/2
        for (int cq = rq; cq < NQ; ++cq) {
            unsigned mask = 0;
            #pragma unroll
            for (int s = 0; s < 16; ++s) {
                int r = rq * 4 + (s >> 2), c = cq * 4 + (s & 3);
                if (r < c && c < NUM_F) mask |= (1u << s);
            }
            tileQ[off++] = (mask << 16) | (unsigned)(rq << 4) | (unsigned)cq;
        }
    }

    // W^T -> fp16 LDS
    for (int q = t; q < DIM * DIM; q += 256) {
        int d = q >> 6, a = q & 63;
        Wt[a][d] = (__half)(_Float16)att_W[q];
    }

    // zero pad row 39 of E
    if (t < NQ) {
        f16x8 z = {};
        *(f16x8*)&e_lds[NROW - 1][t * 8] = z;
    }

    // y_first: wave 0 butterfly
    float yf = (t < NUM_F) ? fo_w[my_idx] * my_fv : 0.f;
    if (wave == 0) {
        #pragma unroll
        for (int m = 1; m < 64; m <<= 1) yf += __shfl_xor(yf, m);
        if (t == 0) s_yfirst = yf;
    }
    __syncthreads();

    // ---------------- phase 1: E staging (fp16) ----------------
    {
        const float4* emb4 = (const float4*)emb_table;
        for (int q = t; q < NUM_F * 8; q += 256) {
            int f = q >> 3, d8 = q & 7;
            float4 v0 = emb4[(size_t)s_idx[f] * 16 + d8 * 2];
            float4 v1 = emb4[(size_t)s_idx[f] * 16 + d8 * 2 + 1];
            float fv = s_fv[f];
            H8 hh;
            hh.h2[0] = __float22half2_rn(make_float2(v0.x * fv, v0.y * fv));
            hh.h2[1] = __float22half2_rn(make_float2(v0.z * fv, v0.w * fv));
            hh.h2[2] = __float22half2_rn(make_float2(v1.x * fv, v1.y * fv));
            hh.h2[3] = __float22half2_rn(make_float2(v1.z * fv, v1.w * fv));
            *(f16x8*)&e_lds[f][d8 * 8] = hh.v;
        }
    }
    __syncthreads();

    // ---------------- hoisted stationary fragments ----------------
    // A-frags = W^T tiles: lane holds row a = n*16+la, k(d) = kf*32 + lg*8 + j
    f16x8 WA[4][2];
    #pragma unroll
    for (int n = 0; n < 4; ++n)
        #pragma unroll
        for (int kf = 0; kf < 2; ++kf)
            WA[n][kf] = *(const f16x8*)&Wt[n * 16 + la][kf * 32 + lg * 8];

    // p_vec as row 0 of a 5th A-tile
    f16x8 PA[2];
    #pragma unroll
    for (int kf = 0; kf < 2; ++kf) {
        H8 P;
        #pragma unroll
        for (int j = 0; j < 8; ++j) {
            float x = (la == 0) ? pv_lds[kf * 32 + lg * 8 + j] : 0.f;
            P.h[j] = (_Float16)x;
        }
        PA[kf] = P.v;
    }

    // bias (accum C-init) and h, per lane's C rows: a = n*16 + lg*4 + i
    f32x4 b4[4], h4[4];
    #pragma unroll
    for (int n = 0; n < 4; ++n) {
        b4[n] = *(const f32x4*)&b_lds[n * 16 + lg * 4];
        h4[n] = *(const f32x4*)&h_lds[n * 16 + lg * 4];
    }
    const f32x4 z4 = {0.f, 0.f, 0.f, 0.f};

    const char* e_base = (const char*)&e_lds[0][0];
    const int   rio = (la >> 2) * (ESTRH * 2) + lg * 16;   // row-quad lane offset
    const int   cio = (la & 3)  * (ESTRH * 2) + lg * 16;   // col-quad lane offset
    const int   vsh = 16 + la;

    // ---------------- phase 2: quad-tile loop (16 pair-slots / tile / wave) ----------------
    #pragma unroll 1
    for (int tile = wave; tile < NTQ; tile += 4) {
        const unsigned rc = tileQ[tile];
        const unsigned rq = (rc >> 4) & 15u;
        const unsigned cq = rc & 15u;
        const bool valid  = (rc >> vsh) & 1u;

        const char* er = e_base + rq * (4 * ESTRH * 2) + rio;
        const char* ec = e_base + cq * (4 * ESTRH * 2) + cio;

        // B-frags = inter: col = la (pair slot), k(d) = kf*32 + lg*8 + j
        H8 er0, er1, ec0, ec1, B0, B1;
        er0.v = *(const f16x8*)(er);
        er1.v = *(const f16x8*)(er + 64);
        ec0.v = *(const f16x8*)(ec);
        ec1.v = *(const f16x8*)(ec + 64);
        #pragma unroll
        for (int i = 0; i < 4; ++i) {
            B0.h2[i] = __hmul2(er0.h2[i], ec0.h2[i]);
            B1.h2[i] = __hmul2(er1.h2[i], ec1.h2[i]);
        }

        // Z^T tiles: D[a][pair]; bias enters as the first MFMA's C operand
        f32x4 a0 = __builtin_amdgcn_mfma_f32_16x16x32_f16(WA[0][0], B0.v, b4[0], 0, 0, 0);
        f32x4 a1 = __builtin_amdgcn_mfma_f32_16x16x32_f16(WA[1][0], B0.v, b4[1], 0, 0, 0);
        f32x4 a2 = __builtin_amdgcn_mfma_f32_16x16x32_f16(WA[2][0], B0.v, b4[2], 0, 0, 0);
        f32x4 a3 = __builtin_amdgcn_mfma_f32_16x16x32_f16(WA[3][0], B0.v, b4[3], 0, 0, 0);
        f32x4 aq = __builtin_amdgcn_mfma_f32_16x16x32_f16(PA[0],    B0.v, z4,    0, 0, 0);
        a0 = __builtin_amdgcn_mfma_f32_16x16x32_f16(WA[0][1], B1.v, a0, 0, 0, 0);
        a1 = __builtin_amdgcn_mfma_f32_16x16x32_f16(WA[1][1], B1.v, a1, 0, 0, 0);
        a2 = __builtin_amdgcn_mfma_f32_16x16x32_f16(WA[2][1], B1.v, a2, 0, 0, 0);
        a3 = __builtin_amdgcn_mfma_f32_16x16x32_f16(WA[3][1], B1.v, a3, 0, 0, 0);
        aq = __builtin_amdgcn_mfma_f32_16x16x32_f16(PA[1],    B1.v, aq, 0, 0, 0);

        // epilogue: sig[pair] = sum_a relu(Zt[a][pair]) * h[a]; 4-way partial tree
        float s0 = fmaxf(a0[0], 0.f) * h4[0][0];
        float s1 = fmaxf(a1[0], 0.f) * h4[1][0];
        float s2 = fmaxf(a2[0], 0.f) * h4[2][0];
        float s3 = fmaxf(a3[0], 0.f) * h4[3][0];
        s0 = fmaf(fmaxf(a0[1], 0.f), h4[0][1], s0);
        s1 = fmaf(fmaxf(a1[1], 0.f), h4[1][1], s1);
        s2 = fmaf(fmaxf(a2[1], 0.f), h4[2][1], s2);
        s3 = fmaf(fmaxf(a3[1], 0.f), h4[3][1], s3);
        s0 = fmaf(fmaxf(a0[2], 0.f), h4[0][2], s0);
        s1 = fmaf(fmaxf(a1[2], 0.f), h4[1][2], s1);
        s2 = fmaf(fmaxf(a2[2], 0.f), h4[2][2], s2);
        s3 = fmaf(fmaxf(a3[2], 0.f), h4[3][2], s3);
        s0 = fmaf(fmaxf(a0[3], 0.f), h4[0][3], s0);
        s1 = fmaf(fmaxf(a1[3], 0.f), h4[1][3], s1);
        s2 = fmaf(fmaxf(a2[3], 0.f), h4[2][3], s2);
        s3 = fmaf(fmaxf(a3[3], 0.f), h4[3][3], s3);
        float ts = (s0 + s1) + (s2 + s3);
        ts += __shfl_xor(ts, 16);
        ts += __shfl_xor(ts, 32);

        if (lg == 0) {
            sq_s[(tile << 4) + la] = valid ? make_float2(ts, aq[0])
                                           : make_float2(-1e30f, 0.f);
        }
    }
    __syncthreads();

    // ---------------- phase 3: softmax + pooling (wave reductions) ----------------
    float sv[4], qv[4];
    #pragma unroll
    for (int i = 0; i < 4; ++i) {
        int p = t + i * 256;
        bool ok = p < NSLOT;
        float2 sq = ok ? sq_s[p] : make_float2(-1e30f, 0.f);
        sv[i] = sq.x;
        qv[i] = sq.y;
    }

    float m3 = fmaxf(fmaxf(sv[0], sv[1]), fmaxf(sv[2], sv[3]));
    #pragma unroll
    for (int mm = 1; mm < 64; mm <<= 1) m3 = fmaxf(m3, __shfl_xor(m3, mm));
    if (lane == 0) wred[wave] = m3;
    __syncthreads();
    const float M = fmaxf(fmaxf(wred[0], wred[1]), fmaxf(wred[2], wred[3]));

    float S = 0.f, Q = 0.f;
    #pragma unroll
    for (int i = 0; i < 4; ++i) {
        float eo = __expf(sv[i] - M);
        S += eo;
        Q += eo * qv[i];
    }
    #pragma unroll
    for (int mm = 1; mm < 64; mm <<= 1) {
        S += __shfl_xor(S, mm);
        Q += __shfl_xor(Q, mm);
    }
    if (lane == 0) { wred[4 + wave] = S; wred[8 + wave] = Q; }
    __syncthreads();

    if (t == 0) {
        const float Ssum = wred[4] + wred[5] + wred[6] + wred[7];
        const float Qsum = wred[8] + wred[9] + wred[10] + wred[11];
        const float att_pool = Qsum / Ssum;
        const float x = bias[0] + s_yfirst + att_pool;
        out[b] = 1.f / (1.f + __expf(-x));
    }
}

extern "C" void kernel_launch(void* const* d_in, const int* in_sizes, int n_in,
                              void* d_out, int out_size, void* d_ws, size_t ws_size,
                              hipStream_t stream) {
    const int*   feat_index = (const int*)  d_in[0];
    const float* feat_value = (const float*)d_in[1];
    const float* fo_w       = (const float*)d_in[2];
    const float* emb_table  = (const float*)d_in[3];
    const float* att_W      = (const float*)d_in[4];
    const float* att_b      = (const float*)d_in[5];
    const float* att_h      = (const float*)d_in[6];
    const float* p_vec      = (const float*)d_in[7];
    const float* bias       = (const float*)d_in[8];
    float*       out        = (float*)d_out;

    const int B = in_sizes[0] / NUM_F;   // 2048

    afm_quad<<<B, 256, 0, stream>>>(feat_index, feat_value, fo_w, emb_table,
                                    att_W, att_b, att_h, p_vec, bias, out);
}

// Round 7
// 32.000 us; speedup vs baseline: 1.1624x; 1.1624x over previous
//
#include <hip/hip_runtime.h>
#include <hip/hip_fp16.h>

#define NUM_F  39
#define NUM_P  741      // 39*38/2
#define NT     48       // tiles, padded (47 real + 1 pad)
#define NPAD   768      // NT * 16
#define DIM    64
#define ESTRH  72       // fp16 row stride in halves; 144 B rows (16B aligned)

typedef float    f32x4 __attribute__((ext_vector_type(4)));
typedef _Float16 f16x8 __attribute__((ext_vector_type(8)));

__global__ __launch_bounds__(256, 3) void afm_mfma7(
    const int*   __restrict__ feat_index,   // [B, F]
    const float* __restrict__ feat_value,   // [B, F]
    const float* __restrict__ fo_w,         // [NUM_FEATS, 1]
    const float* __restrict__ emb_table,    // [NUM_FEATS, 64]
    const float* __restrict__ att_W,        // [64, 64] (d, a)
    const float* __restrict__ att_b,        // [64]
    const float* __restrict__ att_h,        // [64]
    const float* __restrict__ p_vec,        // [64]
    const float* __restrict__ bias,         // [1]
    float*       __restrict__ out)          // [B]
{
    const int b    = blockIdx.x;
    const int t    = threadIdx.x;
    const int wave = t >> 6;
    const int lane = t & 63;
    const int la   = lane & 15;   // pair-within-tile (B col / C col)
    const int lg   = lane >> 4;   // k-group / C row-group

    __shared__ __half         e_lds[NUM_F][ESTRH];  // scaled embeddings, fp16
    __shared__ __half         Wt[DIM][ESTRH];       // W^T fp16: Wt[a][d]
    __shared__ float2         sq_s[NPAD];           // {sig, q}
    __shared__ float          b_lds[DIM], h_lds[DIM], pv_lds[DIM];
    __shared__ unsigned int   pairOff[NPAD];        // r*144 | (c*144 << 16)
    __shared__ int            s_idx[NUM_F];
    __shared__ float          s_fv[NUM_F];
    __shared__ float          s_yfirst;
    __shared__ float          wred[12];             // wave partials: max, S, Q

    // ---------------- phase 0: staging ----------------
    int   my_idx = 0;
    float my_fv  = 0.f;
    if (t < NUM_F) {
        my_idx   = feat_index[b * NUM_F + t];
        my_fv    = feat_value[b * NUM_F + t];
        s_idx[t] = my_idx;
        s_fv[t]  = my_fv;
    }
    if (t < DIM) {
        b_lds[t]  = att_b[t];
        h_lds[t]  = att_h[t];
        pv_lds[t] = p_vec[t];
    }
    if (t < NUM_F) {   // triu(k=1) pair map, row-major; packed LDS byte offsets
        int r = t, off = r * (2 * NUM_F - r - 1) / 2;
        const unsigned int rb = (unsigned int)(r * (ESTRH * 2));
        for (int c = r + 1; c < NUM_F; ++c) {
            pairOff[off] = rb | ((unsigned int)(c * (ESTRH * 2)) << 16);
            ++off;
        }
    }
    if (t < NPAD - NUM_P) pairOff[NUM_P + t] = 0;   // pad -> row 0 reads, stores guarded

    // W^T -> fp16 LDS
    for (int q = t; q < DIM * DIM; q += 256) {
        int d = q >> 6, a = q & 63;
        Wt[a][d] = (__half)(_Float16)att_W[q];
    }

    // y_first: wave 0 butterfly
    float yf = (t < NUM_F) ? fo_w[my_idx] * my_fv : 0.f;
    if (wave == 0) {
        #pragma unroll
        for (int m = 1; m < 64; m <<= 1) yf += __shfl_xor(yf, m);
        if (t == 0) s_yfirst = yf;
    }
    __syncthreads();

    // ---------------- phase 1: E staging (fp16, no unions) ----------------
    {
        const float4* emb4 = (const float4*)emb_table;
        for (int q = t; q < NUM_F * 8; q += 256) {
            int f = q >> 3, d8 = q & 7;
            float4 v0 = emb4[(size_t)s_idx[f] * 16 + d8 * 2];
            float4 v1 = emb4[(size_t)s_idx[f] * 16 + d8 * 2 + 1];
            float fv = s_fv[f];
            f16x8 hv;
            hv[0] = (_Float16)(v0.x * fv);
            hv[1] = (_Float16)(v0.y * fv);
            hv[2] = (_Float16)(v0.z * fv);
            hv[3] = (_Float16)(v0.w * fv);
            hv[4] = (_Float16)(v1.x * fv);
            hv[5] = (_Float16)(v1.y * fv);
            hv[6] = (_Float16)(v1.z * fv);
            hv[7] = (_Float16)(v1.w * fv);
            *(f16x8*)&e_lds[f][d8 * 8] = hv;
        }
    }
    __syncthreads();

    // ---------------- stationary fragments: NAMED SSA variables ----------------
    // A-frags = W^T tiles: lane holds row a = n*16+la, k(d) = kf*32 + lg*8 + j
    const f16x8 WA00 = *(const f16x8*)&Wt[ 0 + la][ 0 + lg * 8];
    const f16x8 WA01 = *(const f16x8*)&Wt[ 0 + la][32 + lg * 8];
    const f16x8 WA10 = *(const f16x8*)&Wt[16 + la][ 0 + lg * 8];
    const f16x8 WA11 = *(const f16x8*)&Wt[16 + la][32 + lg * 8];
    const f16x8 WA20 = *(const f16x8*)&Wt[32 + la][ 0 + lg * 8];
    const f16x8 WA21 = *(const f16x8*)&Wt[32 + la][32 + lg * 8];
    const f16x8 WA30 = *(const f16x8*)&Wt[48 + la][ 0 + lg * 8];
    const f16x8 WA31 = *(const f16x8*)&Wt[48 + la][32 + lg * 8];

    // p_vec as row 0 of a 5th A-tile
    f16x8 PA0 = (f16x8)(_Float16)0.f;
    f16x8 PA1 = (f16x8)(_Float16)0.f;
    if (la == 0) {
        #pragma unroll
        for (int j = 0; j < 8; ++j) {
            PA0[j] = (_Float16)pv_lds[     lg * 8 + j];
            PA1[j] = (_Float16)pv_lds[32 + lg * 8 + j];
        }
    }

    // bias (accum C-init) and h, per lane's C rows: a = n*16 + lg*4 + i
    const f32x4 b40 = *(const f32x4*)&b_lds[ 0 + lg * 4];
    const f32x4 b41 = *(const f32x4*)&b_lds[16 + lg * 4];
    const f32x4 b42 = *(const f32x4*)&b_lds[32 + lg * 4];
    const f32x4 b43 = *(const f32x4*)&b_lds[48 + lg * 4];
    const f32x4 h40 = *(const f32x4*)&h_lds[ 0 + lg * 4];
    const f32x4 h41 = *(const f32x4*)&h_lds[16 + lg * 4];
    const f32x4 h42 = *(const f32x4*)&h_lds[32 + lg * 4];
    const f32x4 h43 = *(const f32x4*)&h_lds[48 + lg * 4];
    const f32x4 z4  = {0.f, 0.f, 0.f, 0.f};

    const char* e_base = (const char*)&e_lds[0][0];
    const int   lgo    = lg * 16;   // byte offset of this lane's 16B k-chunk

    // ---------------- software-pipelined tile loop ----------------
    // prologue: table entries for tile(it=0) and tile(it=1); e-rows for it=0
    unsigned rc_nxt = pairOff[((wave + 4) << 4) + la];
    f16x8 er0, er1, ec0, ec1;
    {
        const unsigned rc = pairOff[(wave << 4) + la];
        const unsigned ro = rc & 0xFFFFu;
        const unsigned co = rc >> 16;
        er0 = *(const f16x8*)(e_base + ro + lgo);
        er1 = *(const f16x8*)(e_base + ro + lgo + 64);
        ec0 = *(const f16x8*)(e_base + co + lgo);
        ec1 = *(const f16x8*)(e_base + co + lgo + 64);
    }

    #pragma unroll 1
    for (int it = 0; it < 12; ++it) {
        const int tile = wave + it * 4;        // < 48
        const int p    = (tile << 4) + la;

        // B-frags = inter for CURRENT tile (consume er/ec now)
        const f16x8 B0 = er0 * ec0;            // 4x v_pk_mul_f16
        const f16x8 B1 = er1 * ec1;

        // prefetch NEXT tile's e-rows (and table entry 2 ahead)
        if (it < 11) {
            const unsigned rc_pf = rc_nxt;
            if (it < 10) rc_nxt = pairOff[((wave + (it + 2) * 4) << 4) + la];
            const unsigned ro = rc_pf & 0xFFFFu;
            const unsigned co = rc_pf >> 16;
            er0 = *(const f16x8*)(e_base + ro + lgo);
            er1 = *(const f16x8*)(e_base + ro + lgo + 64);
            ec0 = *(const f16x8*)(e_base + co + lgo);
            ec1 = *(const f16x8*)(e_base + co + lgo + 64);
        }

        // Z^T tiles: D[a][pair]; bias enters as the first MFMA's C operand
        f32x4 a0 = __builtin_amdgcn_mfma_f32_16x16x32_f16(WA00, B0, b40, 0, 0, 0);
        f32x4 a1 = __builtin_amdgcn_mfma_f32_16x16x32_f16(WA10, B0, b41, 0, 0, 0);
        f32x4 a2 = __builtin_amdgcn_mfma_f32_16x16x32_f16(WA20, B0, b42, 0, 0, 0);
        f32x4 a3 = __builtin_amdgcn_mfma_f32_16x16x32_f16(WA30, B0, b43, 0, 0, 0);
        f32x4 aq = __builtin_amdgcn_mfma_f32_16x16x32_f16(PA0,  B0, z4,  0, 0, 0);
        a0 = __builtin_amdgcn_mfma_f32_16x16x32_f16(WA01, B1, a0, 0, 0, 0);
        a1 = __builtin_amdgcn_mfma_f32_16x16x32_f16(WA11, B1, a1, 0, 0, 0);
        a2 = __builtin_amdgcn_mfma_f32_16x16x32_f16(WA21, B1, a2, 0, 0, 0);
        a3 = __builtin_amdgcn_mfma_f32_16x16x32_f16(WA31, B1, a3, 0, 0, 0);
        aq = __builtin_amdgcn_mfma_f32_16x16x32_f16(PA1,  B1, aq, 0, 0, 0);

        // epilogue: sig[pair] = sum_a relu(Zt[a][pair]) * h[a]; 4 partial chains
        float s0 = fmaxf(a0[0], 0.f) * h40[0];
        float s1 = fmaxf(a1[0], 0.f) * h41[0];
        float s2 = fmaxf(a2[0], 0.f) * h42[0];
        float s3 = fmaxf(a3[0], 0.f) * h43[0];
        s0 = fmaf(fmaxf(a0[1], 0.f), h40[1], s0);
        s1 = fmaf(fmaxf(a1[1], 0.f), h41[1], s1);
        s2 = fmaf(fmaxf(a2[1], 0.f), h42[1], s2);
        s3 = fmaf(fmaxf(a3[1], 0.f), h43[1], s3);
        s0 = fmaf(fmaxf(a0[2], 0.f), h40[2], s0);
        s1 = fmaf(fmaxf(a1[2], 0.f), h41[2], s1);
        s2 = fmaf(fmaxf(a2[2], 0.f), h42[2], s2);
        s3 = fmaf(fmaxf(a3[2], 0.f), h43[2], s3);
        s0 = fmaf(fmaxf(a0[3], 0.f), h40[3], s0);
        s1 = fmaf(fmaxf(a1[3], 0.f), h41[3], s1);
        s2 = fmaf(fmaxf(a2[3], 0.f), h42[3], s2);
        s3 = fmaf(fmaxf(a3[3], 0.f), h43[3], s3);
        float ts = (s0 + s1) + (s2 + s3);
        ts += __shfl_xor(ts, 16);
        ts += __shfl_xor(ts, 32);

        if (lg == 0 && p < NUM_P) {
            sq_s[p] = make_float2(ts, aq[0]);   // q at C row 0
        }
    }
    __syncthreads();

    // ---------------- phase 3: softmax + pooling (wave reductions) ----------------
    float sv0, sv1, sv2, qv0, qv1, qv2;
    {
        float2 x0 = sq_s[t];
        float2 x1 = sq_s[t + 256];
        bool ok2 = (t + 512) < NUM_P;
        float2 x2 = ok2 ? sq_s[t + 512] : make_float2(-1e30f, 0.f);
        sv0 = x0.x; qv0 = x0.y;
        sv1 = x1.x; qv1 = x1.y;
        sv2 = x2.x; qv2 = x2.y;
        // slots NUM_P..768 were never written (pairOff pad) -> exclude
        if (t + 256 >= NUM_P) { sv1 = -1e30f; qv1 = 0.f; }
        if (t >= NUM_P)       { sv0 = -1e30f; qv0 = 0.f; }
    }

    float m3 = fmaxf(fmaxf(sv0, sv1), sv2);
    #pragma unroll
    for (int mm = 1; mm < 64; mm <<= 1) m3 = fmaxf(m3, __shfl_xor(m3, mm));
    if (lane == 0) wred[wave] = m3;
    __syncthreads();
    const float M = fmaxf(fmaxf(wred[0], wred[1]), fmaxf(wred[2], wred[3]));

    float e0 = __expf(sv0 - M);
    float e1 = __expf(sv1 - M);
    float e2 = __expf(sv2 - M);
    float S  = e0 + e1 + e2;
    float Q  = fmaf(e0, qv0, fmaf(e1, qv1, e2 * qv2));
    #pragma unroll
    for (int mm = 1; mm < 64; mm <<= 1) {
        S += __shfl_xor(S, mm);
        Q += __shfl_xor(Q, mm);
    }
    if (lane == 0) { wred[4 + wave] = S; wred[8 + wave] = Q; }
    __syncthreads();

    if (t == 0) {
        const float Ssum = wred[4] + wred[5] + wred[6] + wred[7];
        const float Qsum = wred[8] + wred[9] + wred[10] + wred[11];
        const float att_pool = Qsum / Ssum;
        const float x = bias[0] + s_yfirst + att_pool;
        out[b] = 1.f / (1.f + __expf(-x));
    }
}

extern "C" void kernel_launch(void* const* d_in, const int* in_sizes, int n_in,
                              void* d_out, int out_size, void* d_ws, size_t ws_size,
                              hipStream_t stream) {
    const int*   feat_index = (const int*)  d_in[0];
    const float* feat_value = (const float*)d_in[1];
    const float* fo_w       = (const float*)d_in[2];
    const float* emb_table  = (const float*)d_in[3];
    const float* att_W      = (const float*)d_in[4];
    const float* att_b      = (const float*)d_in[5];
    const float* att_h      = (const float*)d_in[6];
    const float* p_vec      = (const float*)d_in[7];
    const float* bias       = (const float*)d_in[8];
    float*       out        = (float*)d_out;

    const int B = in_sizes[0] / NUM_F;   // 2048

    afm_mfma7<<<B, 256, 0, stream>>>(feat_index, feat_value, fo_w, emb_table,
                                     att_W, att_b, att_h, p_vec, bias, out);
}